// Round 7
// baseline (540.681 us; speedup 1.0000x reference)
//
#include <hip/hip_runtime.h>
#include <math.h>

// ProteinGrid MI355X — round 7: double-buffered half-panel B pipeline in the
// conv kernels. Round 6's convmf_k exposed a full L2 drain per tap
// (barrier -> 32KB global_load_lds -> vmcnt(0) barrier -> compute). Now each
// 32KB tap panel is consumed as two 16KB kq-halves with 2 LDS buffers:
// prefetch(u+1) issues right after the barrier, compute(u) overlaps it, and
// the next barrier's drain finds the load already complete. Same LDS budget
// (3 blocks/CU), same A-stage/tiling/epilogue. MPNN & rest unchanged.

#define EPS_BN 1e-5f

typedef _Float16 f16x8 __attribute__((ext_vector_type(8)));
typedef float f32x4 __attribute__((ext_vector_type(4)));

struct us4 { unsigned short x, y, z, w; };

__device__ __forceinline__ float silu_f(float x) {
  return x / (1.0f + __expf(-x));
}
__device__ __forceinline__ unsigned short f2h(float x) {
  union { _Float16 h; unsigned short u; } v; v.h = (_Float16)x; return v.u;
}
__device__ __forceinline__ float h2f(unsigned short u) {
  union { unsigned short u; _Float16 h; } v; v.u = u; return (float)v.h;
}

// ---------------------------------------------------------------------------
// fp32 GEMM — update MLP only (M=8192). obf=1: fp16 out.
// ---------------------------------------------------------------------------
template<int AMODE, int KTOT>
__global__ __launch_bounds__(256, 2)
void gemm_k(const float* __restrict__ A,
            const float* __restrict__ W,
            const float* __restrict__ bias,
            const float* __restrict__ pscale,
            const float* __restrict__ pshift,
            float* __restrict__ C,
            int act, int obf)
{
  __shared__ __align__(16) float As[32][68];
  __shared__ __align__(16) float Bs[32][128];
  const int t = threadIdx.x;
  const int mbase = blockIdx.x * 64;
  const int m0 = (t >> 4) << 2;
  const int nA = (t & 15) << 2;
  const int ml = t >> 2;
  const int ks = (t & 3) << 3;

  float acc[4][8];
#pragma unroll
  for (int i = 0; i < 4; i++)
#pragma unroll
    for (int j = 0; j < 8; j++) acc[i][j] = 0.f;

  for (int k0 = 0; k0 < KTOT; k0 += 32) {
    {
      const float* src = A + (size_t)(mbase + ml) * KTOT + (k0 + ks);
      const float4 a0 = *(const float4*)src;
      const float4 a1 = *(const float4*)(src + 4);
      As[ks+0][ml]=a0.x; As[ks+1][ml]=a0.y; As[ks+2][ml]=a0.z; As[ks+3][ml]=a0.w;
      As[ks+4][ml]=a1.x; As[ks+5][ml]=a1.y; As[ks+6][ml]=a1.z; As[ks+7][ml]=a1.w;
    }
    {
      const int kl = t >> 3;
      const int ns = (t & 7) << 4;
      const float* wsrc = W + (size_t)(k0 + kl) * 128 + ns;
      *(float4*)&Bs[kl][ns +  0] = *(const float4*)(wsrc + 0);
      *(float4*)&Bs[kl][ns +  4] = *(const float4*)(wsrc + 4);
      *(float4*)&Bs[kl][ns +  8] = *(const float4*)(wsrc + 8);
      *(float4*)&Bs[kl][ns + 12] = *(const float4*)(wsrc + 12);
    }
    __syncthreads();
#pragma unroll 8
    for (int kk = 0; kk < 32; kk++) {
      const float4 av = *(const float4*)&As[kk][m0];
      const float4 b0 = *(const float4*)&Bs[kk][nA];
      const float4 b1 = *(const float4*)&Bs[kk][nA + 64];
      const float a[4]  = {av.x, av.y, av.z, av.w};
      const float bb[8] = {b0.x, b0.y, b0.z, b0.w, b1.x, b1.y, b1.z, b1.w};
#pragma unroll
      for (int i = 0; i < 4; i++)
#pragma unroll
        for (int j = 0; j < 8; j++)
          acc[i][j] = fmaf(a[i], bb[j], acc[i][j]);
    }
    __syncthreads();
  }

  const float rs = rsqrtf(1.f + EPS_BN);
#pragma unroll
  for (int i = 0; i < 4; i++) {
    const size_t row = (size_t)(mbase + m0 + i);
    float v[8];
#pragma unroll
    for (int j = 0; j < 8; j++) {
      const int col = (j < 4) ? (nA + j) : (nA + 60 + j);
      float x = acc[i][j] + bias[col];
      if (act == 1) x = silu_f(x);
      if (pscale) x = fmaf(x, pscale[col] * rs, pshift[col]);
      v[j] = x;
    }
    if (obf) {
      unsigned short* Cb = (unsigned short*)C;
      us4 r0, r1;
      r0.x=f2h(v[0]); r0.y=f2h(v[1]); r0.z=f2h(v[2]); r0.w=f2h(v[3]);
      r1.x=f2h(v[4]); r1.y=f2h(v[5]); r1.z=f2h(v[6]); r1.w=f2h(v[7]);
      *(us4*)&Cb[row * 128 + nA]      = r0;
      *(us4*)&Cb[row * 128 + nA + 64] = r1;
    } else {
      *(float4*)&C[row * 128 + nA]      = make_float4(v[0], v[1], v[2], v[3]);
      *(float4*)&C[row * 128 + nA + 64] = make_float4(v[4], v[5], v[6], v[7]);
    }
  }
}

// ---------------------------------------------------------------------------
// Pack GEMM weight W[K][128] -> fp16 MFMA B-panels [tap][kq][nt][lane][8].
// ---------------------------------------------------------------------------
__global__ __launch_bounds__(256)
void wpack_g_k(const float* __restrict__ w, unsigned short* __restrict__ wp,
               int total)
{
  const int i = blockIdx.x * 256 + threadIdx.x;
  if (i >= total) return;
  const int j   = i & 7;
  const int l   = (i >> 3) & 63;
  const int nt  = (i >> 9) & 7;
  const int kq  = (i >> 12) & 3;
  const int tap = i >> 14;
  const int k = tap * 128 + kq * 32 + (l >> 4) * 8 + j;
  const int n = nt * 16 + (l & 15);
  wp[i] = f2h(w[(size_t)k * 128 + n]);
}

__global__ __launch_bounds__(256)
void cvt_k(const float* __restrict__ src, unsigned short* __restrict__ dst, int n)
{
  const int i = blockIdx.x * 256 + threadIdx.x;
  if (i < n) dst[i] = f2h(src[i]);
}

// ---------------------------------------------------------------------------
// Staging helpers
// ---------------------------------------------------------------------------
__device__ __forceinline__ void stage_b(const unsigned short* g,
                                        unsigned short* dl) {
#pragma unroll
  for (int r = 0; r < 8; r++)
    __builtin_amdgcn_global_load_lds(
        (const __attribute__((address_space(1))) unsigned int*)(g + r * 2048),
        (__attribute__((address_space(3))) unsigned int*)(dl + r * 2048),
        16, 0, 0);
}

// 16KB half-panel: 256 threads x 4 x 16B
__device__ __forceinline__ void stage_half(const unsigned short* g,
                                           unsigned short* dl) {
#pragma unroll
  for (int r = 0; r < 4; r++)
    __builtin_amdgcn_global_load_lds(
        (const __attribute__((address_space(1))) unsigned int*)(g + r * 2048),
        (__attribute__((address_space(3))) unsigned int*)(dl + r * 2048),
        16, 0, 0);
}

__device__ __forceinline__ void mfma_tile(const unsigned short* Aswz,
                                          const unsigned short* Bb,
                                          int mb, int nb, int lx, int lq, int l,
                                          f32x4 acc[2][4]) {
  const int xm = lx & 7;
#pragma unroll
  for (int kq = 0; kq < 4; kq++) {
    f16x8 a0 = *(const f16x8*)(Aswz + (size_t)(((mb + 0) * 16 + lx) * 16 + ((kq * 4 + lq) ^ xm)) * 8);
    f16x8 a1 = *(const f16x8*)(Aswz + (size_t)(((mb + 1) * 16 + lx) * 16 + ((kq * 4 + lq) ^ xm)) * 8);
    const unsigned short* bbase = Bb + (size_t)((kq * 8 + nb) * 64 + l) * 8;
#pragma unroll
    for (int j = 0; j < 4; j++) {
      f16x8 bv = *(const f16x8*)(bbase + (size_t)j * 512);
      acc[0][j] = __builtin_amdgcn_mfma_f32_16x16x32_f16(a0, bv, acc[0][j], 0, 0, 0);
      acc[1][j] = __builtin_amdgcn_mfma_f32_16x16x32_f16(a1, bv, acc[1][j], 0, 0, 0);
    }
  }
}

__device__ __forceinline__ void epi_h(const f32x4 acc[2][4],
                                      const float* bias, int act,
                                      unsigned short* dst,
                                      int mb, int nb, int lx, int lq) {
#pragma unroll
  for (int i = 0; i < 2; i++)
#pragma unroll
    for (int r = 0; r < 4; r++) {
      const int rowloc = (mb + i) * 16 + lq * 4 + r;
#pragma unroll
      for (int j = 0; j < 4; j++) {
        const int col = (nb + j) * 16 + lx;
        float x = acc[i][j][r] + bias[col];
        if (act) x = silu_f(x);
        dst[rowloc * 128 + col] = f2h(x);
      }
    }
}

__device__ __forceinline__ void restage(const unsigned short* src,
                                        unsigned short* Aswz,
                                        int rowl, int seg) {
#pragma unroll
  for (int uu = 0; uu < 4; uu++) {
    uint4 v = *(const uint4*)(src + rowl * 128 + seg * 32 + uu * 8);
    const int u = seg * 4 + uu;
    *(uint4*)(Aswz + (size_t)(rowl * 16 + (u ^ (rowl & 7))) * 8) = v;
  }
}

// ---------------------------------------------------------------------------
// Fused MPNN (unchanged from round 6 — proven).
// ---------------------------------------------------------------------------
__global__ __launch_bounds__(256, 1)
void mpnn_k(const unsigned short* __restrict__ emb16,
            const int* __restrict__ rows,
            const int* __restrict__ cols,
            const float* __restrict__ npos,
            const float* __restrict__ gpos,
            const float* __restrict__ ew1,
            const float* __restrict__ eb1,
            const float* __restrict__ eb2,
            const float* __restrict__ mb1,
            const float* __restrict__ mb2,
            const unsigned short* __restrict__ wall,
            float* __restrict__ aggout)
{
  __shared__ __align__(16) unsigned short Aswz[8192];
  __shared__ __align__(16) unsigned short Cpl[8192];
  __shared__ __align__(16) unsigned short Bb[16384];

  const int t = threadIdx.x;
  const int mbase = blockIdx.x * 64;
  const int l = t & 63, w = t >> 6;
  const int lx = l & 15, lq = l >> 4;
  const int mb = (w >> 1) << 1;
  const int nb = (w & 1) << 2;
  const int rowl = t >> 2;
  const int seg  = t & 3;

  const int e = mbase + rowl;
  const int rr = rows[e];
  const int gg = cols[e];
  const float at0 = npos[rr*3+0], at1 = npos[rr*3+1], at2 = npos[rr*3+2];
  const float at3 = gpos[gg*3+0], at4 = gpos[gg*3+1], at5 = gpos[gg*3+2];

#pragma unroll
  for (int uu = 0; uu < 4; uu++) {
    union { unsigned short h[8]; uint4 v; } pk;
#pragma unroll
    for (int jj = 0; jj < 8; jj++) {
      const int k = seg * 32 + uu * 8 + jj;
      float s = eb1[k];
      s = fmaf(at0, ew1[      k], s);
      s = fmaf(at1, ew1[128 + k], s);
      s = fmaf(at2, ew1[256 + k], s);
      s = fmaf(at3, ew1[384 + k], s);
      s = fmaf(at4, ew1[512 + k], s);
      s = fmaf(at5, ew1[640 + k], s);
      pk.h[jj] = f2h(silu_f(s));
    }
    const int u = seg * 4 + uu;
    *(uint4*)(Aswz + (size_t)(rowl * 16 + (u ^ (rowl & 7))) * 8) = pk.v;
  }
  stage_b(wall + t * 8, Bb + t * 8);
  __syncthreads();

  f32x4 acc1[2][4];
#pragma unroll
  for (int i = 0; i < 2; i++)
#pragma unroll
    for (int j = 0; j < 4; j++) acc1[i][j] = (f32x4){0.f,0.f,0.f,0.f};
  mfma_tile(Aswz, Bb, mb, nb, lx, lq, l, acc1);
  __syncthreads();

  epi_h(acc1, eb2, 0, Cpl, mb, nb, lx, lq);
  {
    const unsigned short* src = emb16 + (size_t)rr * 128 + seg * 32;
#pragma unroll
    for (int uu = 0; uu < 4; uu++) {
      const uint4 v = *(const uint4*)(src + uu * 8);
      const int u = seg * 4 + uu;
      *(uint4*)(Aswz + (size_t)(rowl * 16 + (u ^ (rowl & 7))) * 8) = v;
    }
  }
  stage_b(wall + 16384 + t * 8, Bb + t * 8);
  __syncthreads();

  f32x4 acc2[2][4];
#pragma unroll
  for (int i = 0; i < 2; i++)
#pragma unroll
    for (int j = 0; j < 4; j++) acc2[i][j] = (f32x4){0.f,0.f,0.f,0.f};
  mfma_tile(Aswz, Bb, mb, nb, lx, lq, l, acc2);
  __syncthreads();

  stage_b(wall + 32768 + t * 8, Bb + t * 8);
  restage(Cpl, Aswz, rowl, seg);
  __syncthreads();

  mfma_tile(Aswz, Bb, mb, nb, lx, lq, l, acc2);
  __syncthreads();

  epi_h(acc2, mb1, 1, Cpl, mb, nb, lx, lq);
  stage_b(wall + 49152 + t * 8, Bb + t * 8);
  __syncthreads();

  restage(Cpl, Aswz, rowl, seg);
  __syncthreads();

  f32x4 acc3[2][4];
#pragma unroll
  for (int i = 0; i < 2; i++)
#pragma unroll
    for (int j = 0; j < 4; j++) acc3[i][j] = (f32x4){0.f,0.f,0.f,0.f};
  mfma_tile(Aswz, Bb, mb, nb, lx, lq, l, acc3);
  __syncthreads();

  float* Bf = (float*)Bb;
#pragma unroll
  for (int i = 0; i < 2; i++)
#pragma unroll
    for (int r = 0; r < 4; r++) {
      const int rowloc = (mb + i) * 16 + lq * 4 + r;
#pragma unroll
      for (int j = 0; j < 4; j++) {
        const int col = (nb + j) * 16 + lx;
        Bf[rowloc * 128 + col] = acc3[i][j][r] + mb2[col];
      }
    }
  __syncthreads();

#pragma unroll
  for (int qq = 0; qq < 4; qq++) {
    const int q = t * 4 + qq;
    const int g = q >> 7, c = q & 127;
    float s = 0.f;
#pragma unroll
    for (int r = 0; r < 8; r++) s += Bf[(g * 8 + r) * 128 + c];
    aggout[(size_t)((mbase >> 3) + g) * 128 + c] = s * 0.125f;
  }
}

// ---------------------------------------------------------------------------
// Conv weight repack: thread-per-element (coalesced dst, parallel).
// ---------------------------------------------------------------------------
__global__ __launch_bounds__(256)
void wpack_k(const float* __restrict__ w, unsigned short* __restrict__ wp,
             int T, int total)
{
  const int i = blockIdx.x * 256 + threadIdx.x;
  if (i >= total) return;
  const int j  = i & 7;
  const int l  = (i >> 3) & 63;
  const int nt = (i >> 9) & 7;
  const int kq = (i >> 12) & 3;
  const int r  = i >> 14;            // ib*T + tap
  const int tap = r % T;
  const int ib  = r / T;
  const int o = nt * 16 + (l & 15);
  const int c = kq * 32 + (l >> 4) * 8 + j;
  wp[i] = f2h(w[((size_t)(ib * 128 + o) * 128 + c) * T + tap]);
}

// ---------------------------------------------------------------------------
// fp16 MFMA conv partial — round 7: double-buffered 16KB half-panel pipeline.
// Unit u = (tap*2 + h) lives at wkd + u*8192 (kq-major panel layout).
// Per unit: barrier -> issue prefetch(u+1) -> compute(u) [16 MFMAs/wave].
// ---------------------------------------------------------------------------
template<int KS>
__global__ __launch_bounds__(256, 1)
void convmf_k(const unsigned short* __restrict__ xin,
              const unsigned short* __restrict__ wpack,
              float* __restrict__ part)
{
  constexpr int P  = KS / 2;
  constexpr int SW = 16 + 2 * P;
  constexpr int NU = 2 * KS * KS;     // 16KB units per kd-block
  __shared__ __align__(16) unsigned short Ab[4 * SW * 128];
  __shared__ __align__(16) unsigned short Bb[2][8192];

  const int t   = threadIdx.x;
  const int bx  = blockIdx.x;
  const int kd  = bx >> 7;
  const int rem = bx & 127;
  const int b   = rem >> 6;
  const int z   = (rem >> 2) & 15;
  const int y0  = (rem & 3) << 2;
  const int zz  = z + kd - P;
  float* pout = part + (size_t)kd * (8192 * 128);
  const size_t obase = ((size_t)((b * 16 + z) * 16 + y0) * 16) * 128;

  if ((unsigned)zz >= 16u) {
    float4 zf = make_float4(0, 0, 0, 0);
    float4* dst = (float4*)(pout + obase);
    for (int i = t; i < 2048; i += 256) dst[i] = zf;
    return;
  }

  const int l  = t & 63, w = t >> 6;
  const int lx = l & 15, lq = l >> 4;
  const int mb = (w >> 1) << 1;
  const int nb = (w & 1) << 2;

  f32x4 acc[2][4];
#pragma unroll
  for (int i = 0; i < 2; i++)
#pragma unroll
    for (int j = 0; j < 4; j++) acc[i][j] = (f32x4){0.f, 0.f, 0.f, 0.f};

  const unsigned short* inplane = xin + ((size_t)(b * 16 + zz) * 256) * 128;
  const unsigned short* wkd = wpack + (size_t)(kd * KS * KS) * 16384;

  // prefetch unit 0 into buffer 0
  stage_half(wkd + t * 8, Bb[0] + t * 8);

  int u = 0;
  for (int kh = 0; kh < KS; kh++) {
    __syncthreads();   // prior Ab reads done (also drains any in-flight prefetch)
    // ---- stage A(kh): 4 rows x SW x 16 units of 16B, swizzled ----
    for (int idx = t; idx < 4 * SW * 16; idx += 256) {
      const int ry = idx / (SW * 16);
      const int r2 = idx - ry * (SW * 16);
      const int xs = r2 >> 4;
      const int uu = r2 & 15;
      const int y  = y0 + ry + kh - P;
      const int x  = xs - P;
      uint4 val = make_uint4(0, 0, 0, 0);
      if ((unsigned)y < 16u && (unsigned)x < 16u)
        val = *(const uint4*)(inplane + ((size_t)(y * 16 + x)) * 128 + uu * 8);
      const int du = (ry * SW + xs) * 16 + (uu ^ (xs & 7));
      *(uint4*)(Ab + (size_t)du * 8) = val;
    }
    for (int kw = 0; kw < KS; kw++) {
      const int xsw = lx + kw;
      const int xm  = xsw & 7;
#pragma unroll
      for (int h = 0; h < 2; h++) {
        __syncthreads();   // buf(u) + Ab visible; prior reads of other buf done
        {  // prefetch next unit into the other buffer
          const int nu = (u + 1 < NU) ? (u + 1) : u;
          stage_half(wkd + (size_t)nu * 8192 + t * 8, Bb[(u + 1) & 1] + t * 8);
        }
        const unsigned short* Bcur = Bb[u & 1];
#pragma unroll
        for (int kqh = 0; kqh < 2; kqh++) {
          const int kq = h * 2 + kqh;
          f16x8 a0 = *(const f16x8*)(Ab + (size_t)(((mb + 0) * SW + xsw) * 16 + ((kq * 4 + lq) ^ xm)) * 8);
          f16x8 a1 = *(const f16x8*)(Ab + (size_t)(((mb + 1) * SW + xsw) * 16 + ((kq * 4 + lq) ^ xm)) * 8);
          const unsigned short* bbase = Bcur + (size_t)((kqh * 8 + nb) * 64 + l) * 8;
#pragma unroll
          for (int j = 0; j < 4; j++) {
            f16x8 bv = *(const f16x8*)(bbase + (size_t)j * 512);
            acc[0][j] = __builtin_amdgcn_mfma_f32_16x16x32_f16(a0, bv, acc[0][j], 0, 0, 0);
            acc[1][j] = __builtin_amdgcn_mfma_f32_16x16x32_f16(a1, bv, acc[1][j], 0, 0, 0);
          }
        }
        u++;
      }
    }
  }

#pragma unroll
  for (int i = 0; i < 2; i++) {
    const int my = mb + i;
#pragma unroll
    for (int r = 0; r < 4; r++) {
      const size_t vrow = obase + (size_t)(my * 16 + lq * 4 + r) * 128;
#pragma unroll
      for (int j = 0; j < 4; j++)
        pout[vrow + (nb + j) * 16 + lx] = acc[i][j][r];
    }
  }
}

// ---------------------------------------------------------------------------
__global__ __launch_bounds__(256)
void combine1_k(const float* __restrict__ p,
                const float* __restrict__ g, const float* __restrict__ be,
                unsigned short* __restrict__ o)
{
  const int i = blockIdx.x * 256 + threadIdx.x;
  const size_t off = (size_t)i * 4;
  const int c = (i & 31) * 4;
  float4 a0 = *(const float4*)(p + off);
  float4 a1 = *(const float4*)(p + 1048576 + off);
  float4 a2 = *(const float4*)(p + 2097152 + off);
  const float rs = rsqrtf(1.f + EPS_BN);
  float4 gg = *(const float4*)(g + c);
  float4 bb = *(const float4*)(be + c);
  float v0 = fmaxf(fmaf(a0.x + a1.x + a2.x, gg.x * rs, bb.x), 0.f);
  float v1 = fmaxf(fmaf(a0.y + a1.y + a2.y, gg.y * rs, bb.y), 0.f);
  float v2 = fmaxf(fmaf(a0.z + a1.z + a2.z, gg.z * rs, bb.z), 0.f);
  float v3 = fmaxf(fmaf(a0.w + a1.w + a2.w, gg.w * rs, bb.w), 0.f);
  us4 r; r.x = f2h(v0); r.y = f2h(v1); r.z = f2h(v2); r.w = f2h(v3);
  *(us4*)(o + off) = r;
}

__global__ __launch_bounds__(256)
void combine2_k(const float* __restrict__ p2, const float* __restrict__ p5,
                const float* __restrict__ g2, const float* __restrict__ b2,
                const float* __restrict__ gs, const float* __restrict__ bs,
                unsigned short* __restrict__ o)
{
  const int i = blockIdx.x * 256 + threadIdx.x;
  const size_t off = (size_t)i * 4;
  const int c = (i & 31) * 4;
  float4 s2 = *(const float4*)(p2 + off);
  {
    float4 a1 = *(const float4*)(p2 + 1048576 + off);
    float4 a2 = *(const float4*)(p2 + 2097152 + off);
    s2.x += a1.x + a2.x; s2.y += a1.y + a2.y;
    s2.z += a1.z + a2.z; s2.w += a1.w + a2.w;
  }
  float4 s5 = *(const float4*)(p5 + off);
#pragma unroll
  for (int gi = 1; gi < 5; gi++) {
    float4 a = *(const float4*)(p5 + (size_t)gi * 1048576 + off);
    s5.x += a.x; s5.y += a.y; s5.z += a.z; s5.w += a.w;
  }
  const float rs = rsqrtf(1.f + EPS_BN);
  float4 gg2 = *(const float4*)(g2 + c);
  float4 bb2 = *(const float4*)(b2 + c);
  float4 ggs = *(const float4*)(gs + c);
  float4 bbs = *(const float4*)(bs + c);
  float v0 = fmaxf(fmaf(s2.x, gg2.x * rs, bb2.x) + fmaf(s5.x, ggs.x * rs, bbs.x), 0.f);
  float v1 = fmaxf(fmaf(s2.y, gg2.y * rs, bb2.y) + fmaf(s5.y, ggs.y * rs, bbs.y), 0.f);
  float v2 = fmaxf(fmaf(s2.z, gg2.z * rs, bb2.z) + fmaf(s5.z, ggs.z * rs, bbs.z), 0.f);
  float v3 = fmaxf(fmaf(s2.w, gg2.w * rs, bb2.w) + fmaf(s5.w, ggs.w * rs, bbs.w), 0.f);
  us4 r; r.x = f2h(v0); r.y = f2h(v1); r.z = f2h(v2); r.w = f2h(v3);
  *(us4*)(o + off) = r;
}

// ---------------------------------------------------------------------------
__global__ __launch_bounds__(256)
void pool_partial_k(const unsigned short* __restrict__ xg, float* __restrict__ pmax)
{
  __shared__ float red[256];
  const int bz = blockIdx.x;
  const int t = threadIdx.x;
  const int c = t & 127;
  const int h = t >> 7;
  const unsigned short* base = xg + (size_t)bz * 256 * 128;
  float m = -3.4e38f;
  for (int i = 0; i < 128; i++)
    m = fmaxf(m, h2f(base[(size_t)(h * 128 + i) * 128 + c]));
  red[t] = m;
  __syncthreads();
  if (t < 128) pmax[bz * 128 + t] = fmaxf(red[t], red[t + 128]);
}

__global__ __launch_bounds__(256)
void final_k(const float* __restrict__ pmax,
             const float* __restrict__ fc_w,
             const float* __restrict__ fc_b,
             float* __restrict__ outp)
{
  __shared__ float pool[2][128];
  __shared__ float lg[2][20];
  const int t = threadIdx.x;
  const int b = t >> 7;
  const int c = t & 127;
  float m = -3.4e38f;
  for (int zi = 0; zi < 16; zi++)
    m = fmaxf(m, pmax[(b * 16 + zi) * 128 + c]);
  pool[b][c] = m;
  __syncthreads();
  if (t < 40) {
    const int bb = t / 20, j = t % 20;
    float l = fc_b[j];
    for (int cc = 0; cc < 128; cc++)
      l = fmaf(pool[bb][cc], fc_w[cc * 20 + j], l);
    lg[bb][j] = l;
  }
  __syncthreads();
  if (t < 2) {
    float mx = -3.4e38f;
    for (int j = 0; j < 20; j++) mx = fmaxf(mx, lg[t][j]);
    float s = 0.f;
    for (int j = 0; j < 20; j++) s += expf(lg[t][j] - mx);
    const float ls = mx + logf(s);
    for (int j = 0; j < 20; j++) outp[t * 20 + j] = lg[t][j] - ls;
  }
}

// ---------------------------------------------------------------------------
extern "C" void kernel_launch(void* const* d_in, const int* in_sizes, int n_in,
                              void* d_out, int out_size, void* d_ws, size_t ws_size,
                              hipStream_t stream) {
  (void)in_sizes; (void)n_in; (void)out_size; (void)ws_size;
  const float* node_embedding = (const float*)d_in[0];
  const float* node_pos  = (const float*)d_in[1];
  const float* grid_pos  = (const float*)d_in[2];
  const int*   edge_row  = (const int*)d_in[3];
  const int*   edge_col  = (const int*)d_in[4];
  const float* edge_w1   = (const float*)d_in[5];
  const float* edge_b1   = (const float*)d_in[6];
  const float* edge_w2   = (const float*)d_in[7];
  const float* edge_b2   = (const float*)d_in[8];
  const float* msg_w1    = (const float*)d_in[9];
  const float* msg_b1    = (const float*)d_in[10];
  const float* msg_w2    = (const float*)d_in[11];
  const float* msg_b2    = (const float*)d_in[12];
  const float* upd_w1    = (const float*)d_in[13];
  const float* upd_b1    = (const float*)d_in[14];
  const float* upd_w2    = (const float*)d_in[15];
  const float* upd_b2    = (const float*)d_in[16];
  const float* in_gamma  = (const float*)d_in[17];
  const float* in_beta   = (const float*)d_in[18];
  const float* blk_conv1 = (const float*)d_in[19];
  const float* blk_bn1_g = (const float*)d_in[20];
  const float* blk_bn1_b = (const float*)d_in[21];
  const float* blk_conv2 = (const float*)d_in[22];
  const float* blk_bn2_g = (const float*)d_in[23];
  const float* blk_bn2_b = (const float*)d_in[24];
  const float* blk_conv5 = (const float*)d_in[25];
  const float* blk_bns_g = (const float*)d_in[26];
  const float* blk_bns_b = (const float*)d_in[27];
  const float* fc_w      = (const float*)d_in[28];
  const float* fc_b      = (const float*)d_in[29];

  float* ws = (float*)d_ws;
  unsigned short* wp31 = (unsigned short*)ws;                  // 1,327,104 ush
  unsigned short* wp32 = (unsigned short*)(ws + 663552);       // 1,327,104 ush
  unsigned short* wp5  = (unsigned short*)(ws + 1327104);      // 6,144,000 ush
  float* p1   = ws + 4400128;                // 3 x 1,048,576 f
  float* p2   = ws + 7545856;                // 3 x 1,048,576 f
  float* p5   = ws + 10691584;               // 5 x 1,048,576 f (ends 15,934,464)
  unsigned short* xg0 = (unsigned short*)(ws + 16000000);      // 524,288 f each
  unsigned short* xg1 = (unsigned short*)(ws + 16524288);
  unsigned short* tg  = (unsigned short*)(ws + 17048576);
  float* agg  = ws + 17572864;               // 1,048,576 f
  float* u1   = ws + 18621440;               // 1,048,576 f
  float* pmax = ws + 19670016;               // 4,096 f
  unsigned short* emb16  = (unsigned short*)(ws + 19675136);   // 262,144 ush
  unsigned short* wg_all = (unsigned short*)(ws + 19806208);   // 65,536 ush
  float* outF = (float*)d_out;               // total ~79.4 MB

  // ---- one-time fp16 conversions/packs ----
  cvt_k<<<1024, 256, 0, stream>>>(node_embedding, emb16, 2048 * 128);
  wpack_g_k<<<64, 256, 0, stream>>>(edge_w2, wg_all, 16384);
  wpack_g_k<<<128, 256, 0, stream>>>(msg_w1, wg_all + 16384, 32768);
  wpack_g_k<<<64, 256, 0, stream>>>(msg_w2, wg_all + 49152, 16384);
  wpack_k<<<5184, 256, 0, stream>>>(blk_conv1, wp31, 27, 3 * 27 * 16384);
  wpack_k<<<5184, 256, 0, stream>>>(blk_conv2, wp32, 27, 3 * 27 * 16384);
  wpack_k<<<24000, 256, 0, stream>>>(blk_conv5, wp5, 125, 3 * 125 * 16384);

  // ---- fused MPNN -> agg ----
  mpnn_k<<<1024, 256, 0, stream>>>(
      emb16, edge_row, edge_col, node_pos, grid_pos, edge_w1, edge_b1,
      edge_b2, msg_b1, msg_b2, wg_all, agg);

  // ---- update MLP (fp32); layer2 fuses input-BN, writes fp16 grid ----
  gemm_k<0, 128><<<128, 256, 0, stream>>>(
      agg, upd_w1, upd_b1, nullptr, nullptr, u1, 1, 0);
  gemm_k<0, 128><<<128, 256, 0, stream>>>(
      u1, upd_w2, upd_b2, in_gamma, in_beta, (float*)xg0, 0, 1);

  // ---- 3 residual blocks, fp16 MFMA convs ----
  const unsigned short* xin = xg0;
  unsigned short* xout = xg1;
  for (int i = 0; i < 3; i++) {
    convmf_k<3><<<384, 256, 0, stream>>>(xin, wp31 + (size_t)i * 27 * 16384, p1);
    combine1_k<<<1024, 256, 0, stream>>>(p1, blk_bn1_g + i * 128, blk_bn1_b + i * 128, tg);
    convmf_k<3><<<384, 256, 0, stream>>>(tg, wp32 + (size_t)i * 27 * 16384, p2);
    convmf_k<5><<<640, 256, 0, stream>>>(xin, wp5 + (size_t)i * 125 * 16384, p5);
    combine2_k<<<1024, 256, 0, stream>>>(p2, p5,
        blk_bn2_g + i * 128, blk_bn2_b + i * 128,
        blk_bns_g + i * 128, blk_bns_b + i * 128, xout);
    unsigned short* tmp = (unsigned short*)xin;
    xin = xout;
    xout = tmp;
  }

  // ---- global max pool + fc + log_softmax ----
  pool_partial_k<<<32, 256, 0, stream>>>(xin, pmax);
  final_k<<<1, 256, 0, stream>>>(pmax, fc_w, fc_b, outF);
}